// Round 1
// baseline (522.228 us; speedup 1.0000x reference)
//
#include <hip/hip_runtime.h>

#define IN_F 128
#define HID 256
#define HID2 128

// ---------------- CSR build ----------------
__global__ void count_deg(const int* __restrict__ col, int* __restrict__ deg, int E) {
    int e = blockIdx.x * blockDim.x + threadIdx.x;
    if (e < E) atomicAdd(&deg[col[e]], 1);
}

__global__ __launch_bounds__(1024) void scan_deg(const int* __restrict__ deg,
                                                 int* __restrict__ rp, int n) {
    __shared__ int wsums[16];
    int t = threadIdx.x, lane = t & 63, wid = t >> 6;
    int carry = 0;
    for (int base = 0; base < n; base += 1024) {
        int i = base + t;
        int v = (i < n) ? deg[i] : 0;
        int x = v;
#pragma unroll
        for (int d = 1; d < 64; d <<= 1) {
            int y = __shfl_up(x, d, 64);
            if (lane >= d) x += y;
        }
        if (lane == 63) wsums[wid] = x;
        __syncthreads();
        if (t < 16) {
            int s = wsums[t];
#pragma unroll
            for (int d = 1; d < 16; d <<= 1) {
                int y = __shfl_up(s, d, 64);
                if (t >= d) s += y;
            }
            wsums[t] = s;
        }
        __syncthreads();
        int woff = wid ? wsums[wid - 1] : 0;
        if (i < n) rp[i] = carry + woff + x - v;
        carry += wsums[15];
        __syncthreads();
    }
    if (t == 0) rp[n] = carry;
}

__global__ void fill_csr(const int* __restrict__ row, const int* __restrict__ col,
                         const int* __restrict__ rp, int* __restrict__ fill,
                         int* __restrict__ csr, int E) {
    int e = blockIdx.x * blockDim.x + threadIdx.x;
    if (e < E) {
        int c = col[e];
        int p = atomicAdd(&fill[c], 1);
        csr[rp[c] + p] = row[e];
    }
}

// ---------------- Layer 1 aggregation: out[n,:] = deg_inv[n] * sum x[src,:] ----------------
__global__ __launch_bounds__(128) void agg_gather(const float* __restrict__ x,
                                                  const int* __restrict__ rp,
                                                  const int* __restrict__ csr,
                                                  const int* __restrict__ deg,
                                                  float* __restrict__ out) {
    int n = blockIdx.x, t = threadIdx.x;
    int s = rp[n], e = rp[n + 1];
    float a0 = 0.f, a1 = 0.f;
    int i = s;
    for (; i + 1 < e; i += 2) {
        int s0 = csr[i], s1 = csr[i + 1];
        a0 += x[(size_t)s0 * IN_F + t];
        a1 += x[(size_t)s1 * IN_F + t];
    }
    if (i < e) a0 += x[(size_t)csr[i] * IN_F + t];
    float dinv = 1.f / fmaxf((float)deg[n], 1.f);
    out[(size_t)n * IN_F + t] = (a0 + a1) * dinv;
}

// ---------------- GEMM1: h1 = relu(A[n,128] @ W1[256,128]^T + b1) ----------------
__global__ __launch_bounds__(256) void gemm1_relu(const float* __restrict__ A,
                                                  const float* __restrict__ W,
                                                  const float* __restrict__ b,
                                                  float* __restrict__ out, int n) {
    __shared__ float ash[32][IN_F];
    int m0 = blockIdx.x * 32;
    int vrows = n - m0; if (vrows > 32) vrows = 32;
    const float4* A4 = (const float4*)(A + (size_t)m0 * IN_F);
    float4* s4 = (float4*)&ash[0][0];
    for (int i = threadIdx.x; i < 32 * IN_F / 4; i += 256) {
        int r = i >> 5;  // 32 float4 per row
        float4 v;
        if (r < vrows) v = A4[i]; else v = make_float4(0, 0, 0, 0);
        s4[i] = v;
    }
    __syncthreads();
    int o = threadIdx.x;  // 0..255 output feature
    const float4* w4 = (const float4*)(W + (size_t)o * IN_F);
    float acc[32];
#pragma unroll
    for (int m = 0; m < 32; m++) acc[m] = 0.f;
    for (int k4 = 0; k4 < IN_F / 4; k4++) {
        float4 w = w4[k4];
#pragma unroll
        for (int m = 0; m < 32; m++) {
            float4 a = *(const float4*)&ash[m][k4 * 4];
            acc[m] += a.x * w.x + a.y * w.y + a.z * w.z + a.w * w.w;
        }
    }
    float bo = b[o];
    for (int m = 0; m < vrows; m++)
        out[(size_t)(m0 + m) * HID + o] = fmaxf(acc[m] + bo, 0.f);
}

// ---------------- GEMM2: z2 = h1[n,256] @ W2[128,256]^T (bias/relu deferred) ----------------
__global__ __launch_bounds__(128) void gemm2(const float* __restrict__ A,
                                             const float* __restrict__ W,
                                             float* __restrict__ out, int n) {
    __shared__ float ash[32][HID];
    int m0 = blockIdx.x * 32;
    int vrows = n - m0; if (vrows > 32) vrows = 32;
    const float4* A4 = (const float4*)(A + (size_t)m0 * HID);
    float4* s4 = (float4*)&ash[0][0];
    for (int i = threadIdx.x; i < 32 * HID / 4; i += 128) {
        int r = i >> 6;  // 64 float4 per row
        float4 v;
        if (r < vrows) v = A4[i]; else v = make_float4(0, 0, 0, 0);
        s4[i] = v;
    }
    __syncthreads();
    int o = threadIdx.x;  // 0..127 output feature
    const float4* w4 = (const float4*)(W + (size_t)o * HID);
    float acc[32];
#pragma unroll
    for (int m = 0; m < 32; m++) acc[m] = 0.f;
    for (int k4 = 0; k4 < HID / 4; k4++) {
        float4 w = w4[k4];
#pragma unroll
        for (int m = 0; m < 32; m++) {
            float4 a = *(const float4*)&ash[m][k4 * 4];
            acc[m] += a.x * w.x + a.y * w.y + a.z * w.z + a.w * w.w;
        }
    }
    for (int m = 0; m < vrows; m++)
        out[(size_t)(m0 + m) * HID2 + o] = acc[m];
}

// ------- Layer 2 aggregation fused with bias+relu and final [128]->[2] GEMM -------
__global__ __launch_bounds__(128) void agg2_out(const float* __restrict__ z,
                                                const int* __restrict__ rp,
                                                const int* __restrict__ csr,
                                                const int* __restrict__ deg,
                                                const float* __restrict__ b2,
                                                const float* __restrict__ W3,
                                                const float* __restrict__ b3,
                                                float* __restrict__ out) {
    int n = blockIdx.x, t = threadIdx.x;
    int s = rp[n], e = rp[n + 1];
    float a0 = 0.f, a1 = 0.f;
    int i = s;
    for (; i + 1 < e; i += 2) {
        int s0 = csr[i], s1 = csr[i + 1];
        a0 += z[(size_t)s0 * HID2 + t];
        a1 += z[(size_t)s1 * HID2 + t];
    }
    if (i < e) a0 += z[(size_t)csr[i] * HID2 + t];
    float dinv = 1.f / fmaxf((float)deg[n], 1.f);
    float h = fmaxf((a0 + a1) * dinv + b2[t], 0.f);
    float p0 = h * W3[t];
    float p1 = h * W3[HID2 + t];
    __shared__ float red[4];
#pragma unroll
    for (int d = 32; d > 0; d >>= 1) {
        p0 += __shfl_down(p0, d, 64);
        p1 += __shfl_down(p1, d, 64);
    }
    int wid = t >> 6;
    if ((t & 63) == 0) { red[wid * 2] = p0; red[wid * 2 + 1] = p1; }
    __syncthreads();
    if (t == 0) {
        out[(size_t)n * 2]     = red[0] + red[2] + b3[0];
        out[(size_t)n * 2 + 1] = red[1] + red[3] + b3[1];
    }
}

extern "C" void kernel_launch(void* const* d_in, const int* in_sizes, int n_in,
                              void* d_out, int out_size, void* d_ws, size_t ws_size,
                              hipStream_t stream) {
    const float* x  = (const float*)d_in[0];
    const int*   ei = (const int*)d_in[1];
    const float* W1 = (const float*)d_in[3];
    const float* b1 = (const float*)d_in[4];
    const float* W2 = (const float*)d_in[5];
    const float* b2 = (const float*)d_in[6];
    const float* W3 = (const float*)d_in[7];
    const float* b3 = (const float*)d_in[8];
    float* out = (float*)d_out;

    int N = in_sizes[0] / IN_F;   // 50000
    int E = in_sizes[1] / 2;      // 800000
    const int* row = ei;
    const int* col = ei + E;

    char* base = (char*)d_ws;
    size_t off = 0;
    auto alloc = [&](size_t bytes) -> void* {
        off = (off + 255) & ~(size_t)255;
        void* p = base + off;
        off += bytes;
        return p;
    };
    int*   deg  = (int*)alloc((size_t)2 * N * 4);   // deg + fill contiguous for one memset
    int*   fill = deg + N;
    int*   rp   = (int*)alloc((size_t)(N + 1) * 4);
    int*   csr  = (int*)alloc((size_t)E * 4);
    float* h1   = (float*)alloc((size_t)N * HID * 4);
    float* f2   = (float*)alloc((size_t)N * IN_F * 4);  // agg1, later reused for z2

    hipMemsetAsync(deg, 0, (size_t)2 * N * 4, stream);
    int eb = (E + 255) / 256;
    count_deg<<<eb, 256, 0, stream>>>(col, deg, E);
    scan_deg<<<1, 1024, 0, stream>>>(deg, rp, N);
    fill_csr<<<eb, 256, 0, stream>>>(row, col, rp, fill, csr, E);

    agg_gather<<<N, 128, 0, stream>>>(x, rp, csr, deg, f2);
    int mb = (N + 31) / 32;
    gemm1_relu<<<mb, 256, 0, stream>>>(f2, W1, b1, h1, N);
    gemm2<<<mb, 128, 0, stream>>>(h1, W2, f2, N);     // overwrites agg1 (dead)
    agg2_out<<<N, 128, 0, stream>>>(f2, rp, csr, deg, b2, W3, b3, out);
}